// Round 2
// baseline (652.975 us; speedup 1.0000x reference)
//
#include <hip/hip_runtime.h>
#include <cfloat>

#define KC 512       // codes
#define DD 64        // dim
#define HW 4096      // 64*64
#define NPIX 131072  // 32*64*64
#define QSIZE 8388608  // 32*64*64*64

// numpy pairwise sum of 64 fp32 values (n<=PW_BLOCKSIZE path):
// r[j] = a[j] + a[j+8] + ... + a[j+56] (sequential), then
// ((r0+r1)+(r2+r3)) + ((r4+r5)+(r6+r7)). All ops round-to-nearest, no fma.
__device__ __forceinline__ float np_pairwise_sumsq64(const float* a) {
    float r[8];
    #pragma unroll
    for (int j = 0; j < 8; ++j) r[j] = a[j];
    #pragma unroll
    for (int i = 8; i < 64; i += 8)
        #pragma unroll
        for (int j = 0; j < 8; ++j) r[j] = __fadd_rn(r[j], a[i + j]);
    return __fadd_rn(
        __fadd_rn(__fadd_rn(r[0], r[1]), __fadd_rn(r[2], r[3])),
        __fadd_rn(__fadd_rn(r[4], r[5]), __fadd_rn(r[6], r[7])));
}

// --- prep: w2[k] = fp32 pairwise sum of w_kd^2 (np semantics); zero loss acc
__global__ void prep_kernel(const float* __restrict__ w, float* __restrict__ w2,
                            double* __restrict__ acc) {
    int k = blockIdx.x * blockDim.x + threadIdx.x;
    if (k == 0) *acc = 0.0;
    if (k < KC) {
        float a[DD];
        #pragma unroll
        for (int d = 0; d < DD; ++d) {
            float v = w[k * DD + d];
            a[d] = __fmul_rn(v, v);
        }
        w2[k] = np_pairwise_sumsq64(a);
    }
}

// --- main: fp32-emulated argmin over 512 codes + quant + loss + one-hot enc
__global__ __launch_bounds__(256) void vq_main(
    const float* __restrict__ x, const float* __restrict__ w,
    const float* __restrict__ w2v, float* __restrict__ out_q,
    float* __restrict__ out_enc, float* __restrict__ out_idx,
    double* __restrict__ acc) {

    const int tid = threadIdx.x;
    const int n = blockIdx.x * 256 + tid;
    const int b = n >> 12;        // batch (4096 % 256 == 0, uniform per block)
    const int p = n & 4095;       // h*64+w

    // load this pixel's 64 channels (coalesced across lanes for each d)
    const float* xb = x + (size_t)b * DD * HW + p;
    float xr[DD];
    #pragma unroll
    for (int d = 0; d < DD; ++d) xr[d] = xb[(size_t)d * HW];

    // X = ||x||^2, numpy pairwise fp32 (value must bit-match the np reference:
    // dist quantizes at ulp(64)=7.6e-6, same scale as near-tie gaps)
    float sq[DD];
    #pragma unroll
    for (int d = 0; d < DD; ++d) sq[d] = __fmul_rn(xr[d], xr[d]);
    const float X = np_pairwise_sumsq64(sq);

    // argmin of fp32 dist_k = (X + w2_k) - 2*P_k, P_k = single fma chain
    // over d ascending (BLAS sgemm per-element accumulation order).
    // Strict < keeps first index on ties, matching np.argmin.
    float best = FLT_MAX;
    int bidx = 0;
    for (int k = 0; k < KC; k += 4) {           // 4 codes per iter for ILP
        const float* wk0 = w + (k + 0) * DD;
        const float* wk1 = w + (k + 1) * DD;
        const float* wk2 = w + (k + 2) * DD;
        const float* wk3 = w + (k + 3) * DD;
        float p0 = 0.f, p1 = 0.f, p2 = 0.f, p3 = 0.f;
        #pragma unroll
        for (int d = 0; d < DD; ++d) {
            p0 = __fmaf_rn(xr[d], wk0[d], p0);
            p1 = __fmaf_rn(xr[d], wk1[d], p1);
            p2 = __fmaf_rn(xr[d], wk2[d], p2);
            p3 = __fmaf_rn(xr[d], wk3[d], p3);
        }
        float d0 = __fsub_rn(__fadd_rn(X, w2v[k + 0]), __fadd_rn(p0, p0));
        float d1 = __fsub_rn(__fadd_rn(X, w2v[k + 1]), __fadd_rn(p1, p1));
        float d2 = __fsub_rn(__fadd_rn(X, w2v[k + 2]), __fadd_rn(p2, p2));
        float d3 = __fsub_rn(__fadd_rn(X, w2v[k + 3]), __fadd_rn(p3, p3));
        if (d0 < best) { best = d0; bidx = k + 0; }
        if (d1 < best) { best = d1; bidx = k + 1; }
        if (d2 < best) { best = d2; bidx = k + 2; }
        if (d3 < best) { best = d3; bidx = k + 3; }
    }

    out_idx[n] = (float)bidx;

    // quantized output (NCHW, same addressing as x) + local loss
    const float* wq = w + bidx * DD;    // per-lane gather, L2-resident (128 KB)
    float* qb = out_q + (size_t)b * DD * HW + p;
    float lsum = 0.f;
    #pragma unroll
    for (int d = 0; d < DD; ++d) {
        float q = wq[d];
        float diff = q - xr[d];
        lsum = fmaf(diff, diff, lsum);
        qb[(size_t)d * HW] = q;
    }

    // loss reduce: wave shuffle -> LDS -> one fp64 atomic per block
    #pragma unroll
    for (int off = 32; off > 0; off >>= 1)
        lsum += __shfl_down(lsum, off, 64);
    __shared__ float sred[4];
    if ((tid & 63) == 0) sred[tid >> 6] = lsum;
    __syncthreads();
    if (tid == 0) {
        double t = (double)sred[0] + (double)sred[1] + (double)sred[2] + (double)sred[3];
        atomicAdd(acc, t);
    }

    // one-hot enc rows for this block's 256 pixels (512 KB, coalesced)
    __shared__ int sidx[256];
    sidx[tid] = bidx;
    __syncthreads();

    // enc base byte-address == 4 (mod 16): 3-float head, aligned float4 body, 1 tail
    float* basep = out_enc + (size_t)blockIdx.x * (256 * KC);
    for (int t = tid; t < 32767; t += 256) {
        int u = 3 + 4 * t;
        float4 v;
        #pragma unroll
        for (int j = 0; j < 4; ++j) {
            int e = u + j;
            int row = e >> 9;           // pixel within block
            int col = e & (KC - 1);
            ((float*)&v)[j] = (sidx[row] == col) ? 1.0f : 0.0f;
        }
        *(float4*)(basep + u) = v;
    }
    if (tid < 3) basep[tid] = (sidx[0] == tid) ? 1.0f : 0.0f;
    else if (tid == 3) basep[131071] = (sidx[255] == 511) ? 1.0f : 0.0f;
}

// --- epilogue: loss = vq + commit = 2 * mean((q - x)^2)
__global__ void finish_kernel(const double* __restrict__ acc, float* __restrict__ out) {
    out[0] = (float)(2.0 * (*acc) / (double)QSIZE);
}

extern "C" void kernel_launch(void* const* d_in, const int* in_sizes, int n_in,
                              void* d_out, int out_size, void* d_ws, size_t ws_size,
                              hipStream_t stream) {
    const float* x = (const float*)d_in[0];   // [32,64,64,64] f32 NCHW
    const float* w = (const float*)d_in[1];   // [512,64] f32
    float* out = (float*)d_out;
    float* out_q = out + 1;
    float* out_enc = out_q + QSIZE;
    float* out_idx = out_enc + (size_t)NPIX * KC;

    double* acc = (double*)d_ws;
    float* w2 = (float*)((char*)d_ws + 16);

    prep_kernel<<<2, 256, 0, stream>>>(w, w2, acc);
    vq_main<<<NPIX / 256, 256, 0, stream>>>(x, w, w2, out_q, out_enc, out_idx, acc);
    finish_kernel<<<1, 1, 0, stream>>>(acc, out);
}

// Round 4
// 488.698 us; speedup vs baseline: 1.3362x; 1.3362x over previous
//
#include <hip/hip_runtime.h>
#include <cfloat>

#define KC 512        // codes
#define DD 64         // dim
#define HW 4096       // 64*64
#define NPIX 131072   // 32*64*64
#define QSIZE 8388608 // 32*64*64*64
#define NBLK 512      // NPIX/256

// native vector type for nontemporal 16B stores (HIP float4 is a class — rejected)
typedef float nfloat4 __attribute__((ext_vector_type(4)));

// final combine of numpy pairwise 8-accumulator reduction
__device__ __forceinline__ float np_pairwise8(const float r[8]) {
    return __fadd_rn(
        __fadd_rn(__fadd_rn(r[0], r[1]), __fadd_rn(r[2], r[3])),
        __fadd_rn(__fadd_rn(r[4], r[5]), __fadd_rn(r[6], r[7])));
}

// --- main: fp32-emulated argmin over 512 codes + quant + loss + one-hot enc
// launch_bounds(256,2): grid is 512 blocks = 2 blocks/CU, so allow up to
// 256 VGPR/wave — round-2's VGPR_Count=44 showed xr[64] was spilled to
// scratch, making the hot loop scratch-latency-bound (VALUBusy 34%).
__global__ __launch_bounds__(256, 2) void vq_main(
    const float* __restrict__ x, const float* __restrict__ w,
    float* __restrict__ out_q, float* __restrict__ out_enc,
    float* __restrict__ out_idx, double* __restrict__ partial) {

    const int tid = threadIdx.x;
    const int n = blockIdx.x * 256 + tid;
    const int b = n >> 12;        // batch (4096 % 256 == 0, uniform per block)
    const int p = n & 4095;       // h*64+w

    // w2[k] = numpy-pairwise fp32 sum of w_kd^2, computed per block into LDS
    // (cheap: 2 codes/thread; removes the separate prep dispatch)
    __shared__ float w2s[KC];
    for (int k = tid; k < KC; k += 256) {
        const float* wk = w + k * DD;
        float r[8];
        #pragma unroll
        for (int j = 0; j < 8; ++j) { float v = wk[j]; r[j] = __fmul_rn(v, v); }
        #pragma unroll
        for (int i = 8; i < DD; i += 8)
            #pragma unroll
            for (int j = 0; j < 8; ++j) {
                float v = wk[i + j];
                r[j] = __fadd_rn(r[j], __fmul_rn(v, v));
            }
        w2s[k] = np_pairwise8(r);
    }

    // load this pixel's 64 channels (coalesced across lanes for each d)
    const float* xb = x + (size_t)b * DD * HW + p;
    float xr[DD];
    #pragma unroll
    for (int d = 0; d < DD; ++d) xr[d] = xb[(size_t)d * HW];

    // X = ||x||^2, numpy pairwise fp32 (must bit-match np: dist quantizes at
    // ulp(64)=7.6e-6, same scale as near-tie gaps). 8 rolling accumulators —
    // no sq[64] temp array (that's what triggered the round-2 spill).
    float r8[8];
    #pragma unroll
    for (int j = 0; j < 8; ++j) r8[j] = __fmul_rn(xr[j], xr[j]);
    #pragma unroll
    for (int i = 8; i < DD; i += 8)
        #pragma unroll
        for (int j = 0; j < 8; ++j)
            r8[j] = __fadd_rn(r8[j], __fmul_rn(xr[i + j], xr[i + j]));
    const float X = np_pairwise8(r8);

    __syncthreads();   // w2s ready

    // argmin of fp32 dist_k = (X + w2_k) - 2*P_k, P_k = single fma chain over
    // d ascending (BLAS per-element accumulation). Strict < = first-index tie
    // break, matching np.argmin. w/wk are wave-uniform -> scalar loads.
    float best = FLT_MAX;
    int bidx = 0;
    for (int k = 0; k < KC; k += 4) {           // 4 codes per iter for ILP
        const float* wk0 = w + (k + 0) * DD;
        const float* wk1 = w + (k + 1) * DD;
        const float* wk2 = w + (k + 2) * DD;
        const float* wk3 = w + (k + 3) * DD;
        float p0 = 0.f, p1 = 0.f, p2 = 0.f, p3 = 0.f;
        #pragma unroll
        for (int d = 0; d < DD; ++d) {
            p0 = __fmaf_rn(xr[d], wk0[d], p0);
            p1 = __fmaf_rn(xr[d], wk1[d], p1);
            p2 = __fmaf_rn(xr[d], wk2[d], p2);
            p3 = __fmaf_rn(xr[d], wk3[d], p3);
        }
        float d0 = __fsub_rn(__fadd_rn(X, w2s[k + 0]), __fadd_rn(p0, p0));
        float d1 = __fsub_rn(__fadd_rn(X, w2s[k + 1]), __fadd_rn(p1, p1));
        float d2 = __fsub_rn(__fadd_rn(X, w2s[k + 2]), __fadd_rn(p2, p2));
        float d3 = __fsub_rn(__fadd_rn(X, w2s[k + 3]), __fadd_rn(p3, p3));
        if (d0 < best) { best = d0; bidx = k + 0; }
        if (d1 < best) { best = d1; bidx = k + 1; }
        if (d2 < best) { best = d2; bidx = k + 2; }
        if (d3 < best) { best = d3; bidx = k + 3; }
    }

    out_idx[n] = (float)bidx;

    // quantized output (NCHW, same addressing as x) + local loss
    const float* wq = w + bidx * DD;    // per-lane gather, L2-resident (128 KB)
    float* qb = out_q + (size_t)b * DD * HW + p;
    float lsum = 0.f;
    #pragma unroll
    for (int d = 0; d < DD; ++d) {
        float q = wq[d];
        float diff = q - xr[d];
        lsum = fmaf(diff, diff, lsum);
        __builtin_nontemporal_store(q, qb + (size_t)d * HW);
    }

    // loss reduce: wave shuffle -> LDS -> one plain store per block (no
    // atomics, no zero-init dependency on poisoned ws)
    #pragma unroll
    for (int off = 32; off > 0; off >>= 1)
        lsum += __shfl_down(lsum, off, 64);
    __shared__ float sred[4];
    if ((tid & 63) == 0) sred[tid >> 6] = lsum;
    __syncthreads();
    if (tid == 0)
        partial[blockIdx.x] = (double)sred[0] + (double)sred[1]
                            + (double)sred[2] + (double)sred[3];

    // one-hot enc rows for this block's 256 pixels (512 KB, coalesced,
    // nontemporal: 268 MB stream, keep it out of L2)
    __shared__ int sidx[256];
    sidx[tid] = bidx;
    __syncthreads();

    // enc base byte-address == 4 (mod 16): 3-float head, aligned float4 body, 1 tail
    float* basep = out_enc + (size_t)blockIdx.x * (256 * KC);
    for (int t = tid; t < 32767; t += 256) {
        int u = 3 + 4 * t;
        nfloat4 v;
        #pragma unroll
        for (int j = 0; j < 4; ++j) {
            int e = u + j;
            int row = e >> 9;           // pixel within block
            int col = e & (KC - 1);
            v[j] = (sidx[row] == col) ? 1.0f : 0.0f;
        }
        __builtin_nontemporal_store(v, (nfloat4*)(basep + u));
    }
    if (tid < 3) basep[tid] = (sidx[0] == tid) ? 1.0f : 0.0f;
    else if (tid == 3) basep[131071] = (sidx[255] == 511) ? 1.0f : 0.0f;
}

// --- epilogue: loss = vq + commit = 2 * mean((q - x)^2)
__global__ void finish_kernel(const double* __restrict__ partial,
                              float* __restrict__ out) {
    int t = threadIdx.x;                 // 256 threads, 512 partials
    double s = partial[t] + partial[t + 256];
    #pragma unroll
    for (int off = 32; off > 0; off >>= 1)
        s += __shfl_down(s, off, 64);
    __shared__ double sr[4];
    if ((t & 63) == 0) sr[t >> 6] = s;
    __syncthreads();
    if (t == 0)
        out[0] = (float)(2.0 * (sr[0] + sr[1] + sr[2] + sr[3]) / (double)QSIZE);
}

extern "C" void kernel_launch(void* const* d_in, const int* in_sizes, int n_in,
                              void* d_out, int out_size, void* d_ws, size_t ws_size,
                              hipStream_t stream) {
    const float* x = (const float*)d_in[0];   // [32,64,64,64] f32 NCHW
    const float* w = (const float*)d_in[1];   // [512,64] f32
    float* out = (float*)d_out;
    float* out_q = out + 1;
    float* out_enc = out_q + QSIZE;
    float* out_idx = out_enc + (size_t)NPIX * KC;

    double* partial = (double*)d_ws;          // 512 doubles = 4 KB

    vq_main<<<NBLK, 256, 0, stream>>>(x, w, out_q, out_enc, out_idx, partial);
    finish_kernel<<<1, 256, 0, stream>>>(partial, out);
}